// Round 7
// baseline (1067.000 us; speedup 1.0000x reference)
//
#include <hip/hip_runtime.h>

// Decoder: 12 sequential steps of {attention over 12 enc timesteps, GRU cell, linear->scalar, feedback}.
// B=65536 batch elements independent -> block owns 16 batch elems, 16 lanes per b, 4 dims per lane.
// R6: latency-bound on the per-step dependent chain (R5b: VALUBusy 71%, dur -6% despite fewer instrs).
// VGPR_Count=108 supports 4 waves/SIMD; old __launch_bounds__(256,2) capped residency at 2.
// Single change: __launch_bounds__(256,4) -> 4 blocks/CU, independent barriers overlap.

#define TT 12     // T_IN == T_OUT == 12
#define BB 65536
#define HH 64

typedef _Float16 half8 __attribute__((ext_vector_type(8)));
typedef _Float16 half4 __attribute__((ext_vector_type(4)));
typedef float    f32x4 __attribute__((ext_vector_type(4)));
typedef float    f32x2 __attribute__((ext_vector_type(2)));

#define L2E 1.44269504088896f

__device__ __forceinline__ float ex2(float x){ return __builtin_amdgcn_exp2f(x); }
__device__ __forceinline__ float sigm(float x){ return 1.0f/(1.0f + ex2(-L2E*x)); }
__device__ __forceinline__ float tanh_(float x){ return 1.0f - 2.0f/(ex2(2.0f*L2E*x)+1.0f); }

// DPP row_ror rotate-reduce within the 16-lane row: after ror:1,2,4,8 every lane holds the row sum.
template<int N>
__device__ __forceinline__ float ror_add(float x){
    int s = __builtin_amdgcn_update_dpp(0, __float_as_int(x), 0x120+N, 0xF, 0xF, false);
    return x + __int_as_float(s);
}
__device__ __forceinline__ float sum16(float x){
    x = ror_add<1>(x); x = ror_add<2>(x); x = ror_add<4>(x); x = ror_add<8>(x);
    return x;
}

__global__ __launch_bounds__(256, 4)
void decoder_kernel(const float* __restrict__ enc,    // (12,B,64)
                    const float* __restrict__ hid0,   // (B,64)
                    const float* __restrict__ last0,  // (B,3)
                    const float* __restrict__ Wih,    // (192,3)
                    const float* __restrict__ Whh,    // (192,64)
                    const float* __restrict__ bih,    // (192)
                    const float* __restrict__ bhh,    // (192)
                    const float* __restrict__ Wlin,   // (64)
                    const float* __restrict__ blin,   // (1)
                    float* __restrict__ out)          // (B,12)
{
    __shared__ __align__(16) _Float16 sHi[16*72];
    __shared__ __align__(16) _Float16 sLo[16*72];
    __shared__ __align__(16) float    sGh[16*196];

    const int tid  = threadIdx.x;
    const int wv   = tid >> 6;        // wave 0..3
    const int lane = tid & 63;
    const int q    = lane & 15;       // dim group / MFMA n or m index
    const int quad = lane >> 4;       // which batch elem of this wave (attn phase)
    const int m    = wv*4 + quad;     // batch row within block, 0..15
    const size_t b = (size_t)blockIdx.x*16 + m;

    // ---- one-time loads (all register-resident) ----
    f32x4 e4[TT];
    #pragma unroll
    for (int t=0;t<TT;++t)
        e4[t] = *(const f32x4*)(enc + ((size_t)t*BB + b)*HH + 4*q);

    f32x4 h = *(const f32x4*)(hid0 + b*HH + 4*q);
    float l0 = last0[b*3+0], l1 = last0[b*3+1], l2 = last0[b*3+2];
    float bl = blin[0];

    // GRU input-side weights for this lane's 4 output dims per gate (gate order r,z,n), as f32x4
    f32x4 wr0,wr1,wr2, wz0,wz1,wz2, wn0,wn1,wn2;
    {
        #pragma unroll
        for (int j=0;j<4;++j){
            int r0 = (0*64 + 4*q + j)*3, r1 = (1*64 + 4*q + j)*3, r2 = (2*64 + 4*q + j)*3;
            wr0[j]=Wih[r0+0]; wr1[j]=Wih[r0+1]; wr2[j]=Wih[r0+2];
            wz0[j]=Wih[r1+0]; wz1[j]=Wih[r1+1]; wz2[j]=Wih[r1+2];
            wn0[j]=Wih[r2+0]; wn1[j]=Wih[r2+1]; wn2[j]=Wih[r2+2];
        }
    }
    f32x4 bc0, bc1, bi2, bh2;
    #pragma unroll
    for (int j=0;j<4;++j){
        bc0[j] = bih[      4*q+j] + bhh[      4*q+j];
        bc1[j] = bih[ 64 + 4*q+j] + bhh[ 64 + 4*q+j];
        bi2[j] = bih[128 + 4*q+j];
        bh2[j] = bhh[128 + 4*q+j];
    }
    f32x4 wl = *(const f32x4*)(Wlin + 4*q);

    // W_hh^T B-fragments, hi/lo fp16 split, register-resident: wave covers N-chunks 3wv..3wv+2.
    // B-frag layout: n = lane&15, k = kc*32 + quad*8 + jj.
    half8 wfhi[3][2], wflo[3][2];
    #pragma unroll
    for (int c=0;c<3;++c){
        int jout = (wv*3+c)*16 + q;
        #pragma unroll
        for (int kc=0;kc<2;++kc){
            const float* src = Whh + jout*64 + kc*32 + quad*8;
            half8 vh, vl;
            #pragma unroll
            for (int jj=0;jj<8;++jj){
                float w = src[jj];
                _Float16 whi = (_Float16)w;
                vh[jj] = whi;
                vl[jj] = (_Float16)(w - (float)whi);
            }
            wfhi[c][kc] = vh;
            wflo[c][kc] = vl;
        }
    }

    // ---- 12 sequential decoder steps ----
    for (int s=0;s<TT;++s){
        // attention logits: packed dot (2x v_pk ops + horizontal add) + DPP rotate-reduce
        float a[TT];
        #pragma unroll
        for (int t=0;t<TT;++t){
            f32x2 p2 = e4[t].xy * h.xy;
            p2 += e4[t].zw * h.zw;
            a[t] = sum16(p2.x + p2.y);
        }
        // max (tree)
        float mx01 = fmaxf(a[0],a[1]), mx23 = fmaxf(a[2],a[3]), mx45 = fmaxf(a[4],a[5]);
        float mx67 = fmaxf(a[6],a[7]), mx89 = fmaxf(a[8],a[9]), mxab = fmaxf(a[10],a[11]);
        float mx = fmaxf(fmaxf(fmaxf(mx01,mx23),fmaxf(mx45,mx67)),fmaxf(mx89,mxab));
        float nm = -mx*L2E;
        #pragma unroll
        for (int t=0;t<TT;++t) a[t] = ex2(__builtin_fmaf(a[t], L2E, nm));
        // sum (tree)
        float s01=a[0]+a[1], s23=a[2]+a[3], s45=a[4]+a[5], s67=a[6]+a[7], s89=a[8]+a[9], sab=a[10]+a[11];
        float ss = ((s01+s23)+(s45+s67)) + (s89+sab);
        float inv = 1.0f/ss;
        // context: dual f32x4 accumulators (v_pk_fma_f32), then h += ctx*inv
        f32x4 ctxA = {0.f,0.f,0.f,0.f}, ctxB = {0.f,0.f,0.f,0.f};
        #pragma unroll
        for (int t=0;t<TT;t+=2){
            ctxA += e4[t]   * (f32x4)(a[t]);
            ctxB += e4[t+1] * (f32x4)(a[t+1]);
        }
        h += (ctxA + ctxB) * (f32x4)(inv);

        // stage h into LDS as fp16 hi + lo residual (~2^-22 combined)
        half4 hhi, hlo;
        #pragma unroll
        for (int j=0;j<4;++j){
            _Float16 hh = (_Float16)h[j];
            hhi[j] = hh;
            hlo[j] = (_Float16)(h[j] - (float)hh);
        }
        *(half4*)&sHi[m*72 + 4*q] = hhi;
        *(half4*)&sLo[m*72 + 4*q] = hlo;
        __syncthreads();

        // MFMA: gh[m][jout] = sum_k h[m][k] * Whh[jout][k]; terms hi*Whi + hi*Wlo + lo*Whi.
        // A-frag layout: row = lane&15 (=q), k = quad*8 + kc*32.
        half8 ahi0 = *(half8*)&sHi[q*72 +  0 + quad*8];
        half8 ahi1 = *(half8*)&sHi[q*72 + 32 + quad*8];
        half8 alo0 = *(half8*)&sLo[q*72 +  0 + quad*8];
        half8 alo1 = *(half8*)&sLo[q*72 + 32 + quad*8];
        #pragma unroll
        for (int c=0;c<3;++c){
            f32x4 acc = {0.f,0.f,0.f,0.f};
            acc = __builtin_amdgcn_mfma_f32_16x16x32_f16(ahi0, wfhi[c][0], acc, 0,0,0);
            acc = __builtin_amdgcn_mfma_f32_16x16x32_f16(ahi1, wfhi[c][1], acc, 0,0,0);
            acc = __builtin_amdgcn_mfma_f32_16x16x32_f16(ahi0, wflo[c][0], acc, 0,0,0);
            acc = __builtin_amdgcn_mfma_f32_16x16x32_f16(ahi1, wflo[c][1], acc, 0,0,0);
            acc = __builtin_amdgcn_mfma_f32_16x16x32_f16(alo0, wfhi[c][0], acc, 0,0,0);
            acc = __builtin_amdgcn_mfma_f32_16x16x32_f16(alo1, wfhi[c][1], acc, 0,0,0);
            int jcol = (wv*3+c)*16 + q;
            // C/D layout: col = lane&15, row = quad*4 + reg
            #pragma unroll
            for (int r=0;r<4;++r)
                sGh[(quad*4+r)*196 + jcol] = acc[r];
        }
        __syncthreads();

        // gates: r=sig(i_r+h_r), z=sig(i_z+h_z), n=tanh(i_n + r*(h_n+b_hh_n)), h'=(1-z)n+z*h
        f32x4 ghr = *(f32x4*)&sGh[m*196 +   0 + 4*q];
        f32x4 ghz = *(f32x4*)&sGh[m*196 +  64 + 4*q];
        f32x4 ghn = *(f32x4*)&sGh[m*196 + 128 + 4*q];

        // packed pre-activations
        f32x4 gr4 = bc0 + ghr;  gr4 += wr0*(f32x4)(l0); gr4 += wr1*(f32x4)(l1); gr4 += wr2*(f32x4)(l2);
        f32x4 gz4 = bc1 + ghz;  gz4 += wz0*(f32x4)(l0); gz4 += wz1*(f32x4)(l1); gz4 += wz2*(f32x4)(l2);
        f32x4 gn4 = bi2;        gn4 += wn0*(f32x4)(l0); gn4 += wn1*(f32x4)(l1); gn4 += wn2*(f32x4)(l2);
        f32x4 hb  = ghn + bh2;

        float o = 0.f;
        #pragma unroll
        for (int j=0;j<4;++j){
            float r = sigm(gr4[j]);
            float z = sigm(gz4[j]);
            float n = tanh_(gn4[j] + r*hb[j]);
            float hn = (1.f - z)*n + z*h[j];
            h[j] = hn;
            o += hn * wl[j];
        }
        // out = h' . W_lin + b_lin, DPP rotate-reduce over 16-lane group
        o = sum16(o) + bl;
        if (q == 0) out[b*TT + s] = o;
        // last = [out, last[0], last[1]]
        l2 = l1; l1 = l0; l0 = o;
    }
}

extern "C" void kernel_launch(void* const* d_in, const int* in_sizes, int n_in,
                              void* d_out, int out_size, void* d_ws, size_t ws_size,
                              hipStream_t stream)
{
    const float* enc  = (const float*)d_in[0];
    const float* hid0 = (const float*)d_in[1];
    const float* lst  = (const float*)d_in[2];
    const float* Wih  = (const float*)d_in[3];
    const float* Whh  = (const float*)d_in[4];
    const float* bih  = (const float*)d_in[5];
    const float* bhh  = (const float*)d_in[6];
    const float* Wlin = (const float*)d_in[7];
    const float* blin = (const float*)d_in[8];
    decoder_kernel<<<BB/16, 256, 0, stream>>>(enc, hid0, lst, Wih, Whh, bih, bhh,
                                              Wlin, blin, (float*)d_out);
}